// Round 8
// baseline (132.489 us; speedup 1.0000x reference)
//
#include <hip/hip_runtime.h>
#include <hip/hip_bf16.h>
#include <cstdint>

typedef __bf16 bf16x8 __attribute__((ext_vector_type(8)));
typedef float f32x4 __attribute__((ext_vector_type(4)));

#define MFMA16(a, b, c) __builtin_amdgcn_mfma_f32_16x16x32_bf16((a), (b), (c), 0, 0, 0)

// async global->LDS DMA, 16B per lane. lds ptr must be wave-uniform; HW writes
// lane i's 16B to lds + i*16. global src is per-lane.
#define GLL16(g, l) __builtin_amdgcn_global_load_lds( \
    (const __attribute__((address_space(1))) unsigned int*)(g), \
    (__attribute__((address_space(3))) unsigned int*)(l), 16, 0, 0)

// ---------- helpers ----------
__device__ __forceinline__ unsigned short f2bf(float f) {
  union { float f; unsigned u; } v; v.f = f;
  unsigned u = v.u;
  u += 0x7fffu + ((u >> 16) & 1u);   // RNE (finite data only)
  return (unsigned short)(u >> 16);
}
__device__ __forceinline__ unsigned pk2(float a, float b) {
  __hip_bfloat162 h = __float22bfloat162_rn(make_float2(a, b));  // v_cvt_pk_bf16_f32
  union { __hip_bfloat162 h; unsigned u; } v; v.h = h; return v.u;
}

// ---------- kernel 1: W [1024][128] f32 -> Wt bf16 [3][128][1024] (n-major) ----------
__global__ __launch_bounds__(256) void convert_w(
    const float* __restrict__ Wq, const float* __restrict__ Wk,
    const float* __restrict__ Wv, unsigned short* __restrict__ wt) {
  int idx = blockIdx.x * 256 + threadIdx.x;     // 0 .. 393215
  int m = idx >> 17;
  int rem = idx & 131071;
  int k = rem >> 7;
  int n = rem & 127;
  const float* W = (m == 0) ? Wq : (m == 1) ? Wk : Wv;
  wt[(size_t)m * 131072 + (size_t)n * 1024 + k] = f2bf(W[(size_t)k * 128 + n]);
}

// ---------- kernel 2: QKV projection GEMM ----------
__global__ __launch_bounds__(256) void qkv_gemm(
    const float* __restrict__ x, const unsigned short* __restrict__ wt_all,
    const float* __restrict__ bq, const float* __restrict__ bk,
    const float* __restrict__ bv,
    unsigned short* __restrict__ Qg, unsigned short* __restrict__ Kg,
    unsigned short* __restrict__ Vtg) {
  __shared__ unsigned short x_lds[128][40];   // +8 pad
  __shared__ unsigned short w_lds[128][40];
  const int tid = threadIdx.x;
  const int lane = tid & 63;
  const int w = tid >> 6;
  const int mode = blockIdx.y;
  const int m0 = blockIdx.x * 128;
  const unsigned short* wt = wt_all + (size_t)mode * 131072;
  const float* bias = (mode == 0) ? bq : (mode == 1) ? bk : bv;

  const int wr = (w >> 1) * 64;
  const int wc = (w & 1) * 64;
  const int lr = lane & 15;
  const int lk = (lane >> 4) * 8;

  f32x4 acc[4][4];
#pragma unroll
  for (int m = 0; m < 4; ++m)
#pragma unroll
    for (int n = 0; n < 4; ++n) acc[m][n] = (f32x4){0.f, 0.f, 0.f, 0.f};

  const int srow = tid >> 1;
  const int shalf = (tid & 1) * 16;
  const float* xrow = x + (size_t)(m0 + srow) * 1024 + shalf;
  const unsigned short* wrow = wt + (size_t)srow * 1024 + shalf;

  float4 xa, xb, xc, xd; uint4 wv0, wv1;
  {
    const float4* s4 = (const float4*)xrow;
    xa = s4[0]; xb = s4[1]; xc = s4[2]; xd = s4[3];
    const uint4* ws4 = (const uint4*)wrow;
    wv0 = ws4[0]; wv1 = ws4[1];
  }

  for (int k0 = 0; k0 < 1024; k0 += 32) {
    __syncthreads();
    {
      uint4 w0, w1;
      w0.x = pk2(xa.x, xa.y);  w0.y = pk2(xa.z, xa.w);
      w0.z = pk2(xb.x, xb.y);  w0.w = pk2(xb.z, xb.w);
      w1.x = pk2(xc.x, xc.y);  w1.y = pk2(xc.z, xc.w);
      w1.z = pk2(xd.x, xd.y);  w1.w = pk2(xd.z, xd.w);
      *(uint4*)&x_lds[srow][shalf] = w0;
      *(uint4*)&x_lds[srow][shalf + 8] = w1;
      *(uint4*)&w_lds[srow][shalf] = wv0;
      *(uint4*)&w_lds[srow][shalf + 8] = wv1;
    }
    __syncthreads();
    if (k0 + 32 < 1024) {
      const float4* s4 = (const float4*)(xrow + k0 + 32);
      xa = s4[0]; xb = s4[1]; xc = s4[2]; xd = s4[3];
      const uint4* ws4 = (const uint4*)(wrow + k0 + 32);
      wv0 = ws4[0]; wv1 = ws4[1];
    }
    bf16x8 af[4], bfr[4];
#pragma unroll
    for (int m = 0; m < 4; ++m) af[m] = *(const bf16x8*)&x_lds[wr + m * 16 + lr][lk];
#pragma unroll
    for (int n = 0; n < 4; ++n) bfr[n] = *(const bf16x8*)&w_lds[wc + n * 16 + lr][lk];
#pragma unroll
    for (int m = 0; m < 4; ++m)
#pragma unroll
      for (int n = 0; n < 4; ++n) acc[m][n] = MFMA16(af[m], bfr[n], acc[m][n]);
  }

  float bcol[4];
#pragma unroll
  for (int n = 0; n < 4; ++n) bcol[n] = bias[wc + n * 16 + lr];
#pragma unroll
  for (int m = 0; m < 4; ++m)
#pragma unroll
    for (int n = 0; n < 4; ++n)
#pragma unroll
      for (int r = 0; r < 4; ++r) {
        int grow = m0 + wr + m * 16 + (lane >> 4) * 4 + r;
        int col = wc + n * 16 + lr;
        float val = acc[m][n][r] + bcol[n];
        if (mode == 0) {
          val *= 0.08838834764831845f;  // 1/sqrt(128)
          Qg[(size_t)grow * 128 + col] = f2bf(val);
        } else if (mode == 1) {
          Kg[(size_t)grow * 128 + col] = f2bf(val);
        } else {
          int bb = grow >> 12, s = grow & 4095;
          Vtg[((size_t)bb * 128 + col) * 4096 + s] = f2bf(val);
        }
      }
}

// ---------- attention LDS: double-buffered, DMA-linear, 16B-chunk XOR swizzle ----------
// K[buf][row][.]: chunk16 c stored at physical chunk c ^ (row&7). Same for V.
struct AttnLds {
  unsigned short K_lds[2][64][128];   // 32 KB
  unsigned short V_lds[2][128][64];   // 32 KB
  unsigned short P_lds[4][16][68];    // 8.5 KB
};

// Issue 8 async DMA loads (4 K-chunks + 4 V-chunks of 1 KB) for KV tile at k0.
__device__ __forceinline__ void stage_kv(AttnLds& S, int buf,
    const unsigned short* __restrict__ Kb, const unsigned short* __restrict__ Vb,
    int k0, int w, int lane) {
#pragma unroll
  for (int j = 0; j < 4; ++j) {
    const int cid = j * 4 + w;                 // 1KB chunk id, wave-uniform
    {
      const int s = cid * 64 + lane;           // 16B slot in K tile
      const int row = s >> 4, cp = s & 15;
      const int csrc = cp ^ (row & 7);         // inverse swizzle on SOURCE
      GLL16(Kb + (size_t)(k0 + row) * 128 + csrc * 8,
            &S.K_lds[buf][0][0] + cid * 512);
    }
    {
      const int s = cid * 64 + lane;           // 16B slot in V tile
      const int row = s >> 3, cp = s & 7;
      const int csrc = cp ^ (row & 7);
      GLL16(Vb + (size_t)row * 4096 + k0 + csrc * 8,
            &S.V_lds[buf][0][0] + cid * 512);
    }
  }
}

// ---------- attention tile body: swapped QK^T, in-register softmax, async DMA dbuf ----------
__device__ __forceinline__ void attn_tiles(
    AttnLds& S, const unsigned short* __restrict__ Kg,
    const unsigned short* __restrict__ Vtg, const float* __restrict__ pmask,
    int b, int q0, int tstart, int tend,
    const bf16x8 (&qf)[4], float& mrow, float& lsum, f32x4 (&o)[8]) {
  const int tid = threadIdx.x;
  const int lane = tid & 63;
  const int w = tid >> 6;
  const int lr = lane & 15;
  const int lg = lane >> 4;
  const int sw = lr & 7;                       // read-side swizzle key
  const int q_own = q0 + w * 16 + lr;
  const unsigned short* Kb = Kg + (size_t)b * 4096 * 128;
  const unsigned short* Vb = Vtg + (size_t)b * 128 * 4096;

  int buf = 0;
  stage_kv(S, 0, Kb, Vb, tstart * 64, w, lane);

  for (int t = tstart; t < tend; ++t) {
    const int k0 = t * 64;
    __syncthreads();   // vmcnt-drain: DMA for buf complete; all waves synced
    if (t + 1 < tend) stage_kv(S, buf ^ 1, Kb, Vb, (t + 1) * 64, w, lane);

    // S^T: st[f][r] = S[k = k0+16f+4lg+r][q_own]
    f32x4 st[4];
    __builtin_amdgcn_s_setprio(1);
#pragma unroll
    for (int f = 0; f < 4; ++f) {
      st[f] = (f32x4){0.f, 0.f, 0.f, 0.f};
#pragma unroll
      for (int dc = 0; dc < 4; ++dc) {
        bf16x8 kf = *(const bf16x8*)&S.K_lds[buf][f * 16 + lr][(((dc << 2) | lg) ^ sw) << 3];
        st[f] = MFMA16(kf, qf[dc], st[f]);   // swapped: K as A, Q as B
      }
    }
    __builtin_amdgcn_s_setprio(0);

    // padding mask via ballot (one coalesced load per wave)
    const unsigned long long mb = __ballot(pmask[(size_t)b * 4096 + k0 + lane] > 0.f);
    unsigned nib[4];
#pragma unroll
    for (int f = 0; f < 4; ++f) nib[f] = (unsigned)(mb >> (16 * f + 4 * lg)) & 0xFu;

    float mx = -1e30f;
    if (k0 + 63 > q0 + (w << 4)) {           // diagonal tile: causal + pad
#pragma unroll
      for (int f = 0; f < 4; ++f)
#pragma unroll
        for (int r = 0; r < 4; ++r) {
          const bool ok = (((nib[f] >> r) & 1u) != 0u) &&
                          (k0 + 16 * f + 4 * lg + r <= q_own);
          const float s = ok ? st[f][r] : -1e30f;
          st[f][r] = s;
          mx = fmaxf(mx, s);
        }
    } else {                                  // interior tile: pad mask only
#pragma unroll
      for (int f = 0; f < 4; ++f)
#pragma unroll
        for (int r = 0; r < 4; ++r) {
          const bool ok = ((nib[f] >> r) & 1u) != 0u;
          const float s = ok ? st[f][r] : -1e30f;
          st[f][r] = s;
          mx = fmaxf(mx, s);
        }
    }
    mx = fmaxf(mx, __shfl_xor(mx, 16));
    mx = fmaxf(mx, __shfl_xor(mx, 32));
    const float mnew = fmaxf(mrow, mx);
    const float alpha = __expf(mrow - mnew);
    mrow = mnew;

    float sum = 0.f;
#pragma unroll
    for (int f = 0; f < 4; ++f) {
      const float p0 = (st[f][0] < -1e29f) ? 0.f : __expf(st[f][0] - mnew);
      const float p1 = (st[f][1] < -1e29f) ? 0.f : __expf(st[f][1] - mnew);
      const float p2 = (st[f][2] < -1e29f) ? 0.f : __expf(st[f][2] - mnew);
      const float p3 = (st[f][3] < -1e29f) ? 0.f : __expf(st[f][3] - mnew);
      sum += (p0 + p1) + (p2 + p3);
      uint2 u; u.x = pk2(p0, p1); u.y = pk2(p2, p3);
      *(uint2*)&S.P_lds[w][lr][16 * f + 4 * lg] = u;   // P[q_own][k-chunk]
    }
    sum += __shfl_xor(sum, 16);
    sum += __shfl_xor(sum, 32);
    lsum = lsum * alpha + sum;
#pragma unroll
    for (int n = 0; n < 8; ++n) o[n] *= alpha;

    __asm__ volatile("s_waitcnt lgkmcnt(0)" ::: "memory");
    // O^T: o[n][r] = O[q_own][d = n*16+4lg+r]
    __builtin_amdgcn_s_setprio(1);
#pragma unroll
    for (int kc = 0; kc < 2; ++kc) {
      bf16x8 pa = *(const bf16x8*)&S.P_lds[w][lr][kc * 32 + lg * 8];
#pragma unroll
      for (int n = 0; n < 8; ++n) {
        bf16x8 vf = *(const bf16x8*)&S.V_lds[buf][n * 16 + lr][(((kc << 2) | lg) ^ sw) << 3];
        o[n] = MFMA16(vf, pa, o[n]);         // swapped: V as A, P as B
      }
    }
    __builtin_amdgcn_s_setprio(0);
    buf ^= 1;
  }
}

// ---------- kernel 3a: fallback monolithic flash attention ----------
__global__ __launch_bounds__(256) void attn_fwd(
    const unsigned short* __restrict__ Qg, const unsigned short* __restrict__ Kg,
    const unsigned short* __restrict__ Vtg, const float* __restrict__ pmask,
    float* __restrict__ out) {
  __shared__ AttnLds S;
  const int tid = threadIdx.x;
  const int lane = tid & 63;
  const int w = tid >> 6;
  const int b = blockIdx.y;
  const int q0 = blockIdx.x * 64;
  const int lr = lane & 15;
  const int lg = lane >> 4;
  const int lk = lg * 8;

  bf16x8 qf[4];
  {
    const unsigned short* qp = Qg + ((size_t)b * 4096 + q0 + w * 16 + lr) * 128;
#pragma unroll
    for (int dc = 0; dc < 4; ++dc) qf[dc] = *(const bf16x8*)(qp + dc * 32 + lk);
  }
  float mrow = -1e30f, lsum = 0.f;
  f32x4 o[8];
#pragma unroll
  for (int n = 0; n < 8; ++n) o[n] = (f32x4){0.f, 0.f, 0.f, 0.f};

  attn_tiles(S, Kg, Vtg, pmask, b, q0, 0, (q0 >> 6) + 1, qf, mrow, lsum, o);

  const int qrow = q0 + w * 16 + lr;
  const bool alive = pmask[(size_t)b * 4096 + qrow] > 0.f;
  const float inv = (alive && lsum > 0.f) ? 1.f / lsum : 0.f;
  float* op = out + ((size_t)b * 4096 + qrow) * 128 + 4 * lg;
#pragma unroll
  for (int n = 0; n < 8; ++n) {
    f32x4 v = o[n] * inv;
    *(f32x4*)(op + n * 16) = v;
  }
}

// ---------- kernel 3b: split-KV flash attention, XCD-pinned, f32 partials ----------
__global__ __launch_bounds__(256) void attn_split(
    const unsigned short* __restrict__ Qg, const unsigned short* __restrict__ Kg,
    const unsigned short* __restrict__ Vtg, const float* __restrict__ pmask,
    float* __restrict__ out, float* __restrict__ o_part,
    float* __restrict__ ml_part) {
  __shared__ AttnLds S;
  const int tid = threadIdx.x;
  const int lane = tid & 63;
  const int w = tid >> 6;
  const int L = blockIdx.x;
  const int xcd = L & 7;
  const int b = xcd >> 1;
  const int s = ((L >> 3) << 1) | (xcd & 1);   // 0..159 within batch
  int qb, c, nch;
  if (s < 16)      { qb = s;                c = 0;          nch = 1; }
  else if (s < 48) { int t = s - 16; qb = 16 + (t >> 1); c = t & 1;  nch = 2; }
  else if (s < 96) { int t = s - 48; qb = 32 + t / 3;    c = t % 3;  nch = 3; }
  else             { int t = s - 96; qb = 48 + (t >> 2); c = t & 3;  nch = 4; }
  const int q0 = qb * 64;
  const int tstart = c * 16;
  const int tend = min(c * 16 + 16, qb + 1);
  const int lr = lane & 15;
  const int lg = lane >> 4;
  const int lk = lg * 8;

  bf16x8 qf[4];
  {
    const unsigned short* qp = Qg + ((size_t)b * 4096 + q0 + w * 16 + lr) * 128;
#pragma unroll
    for (int dc = 0; dc < 4; ++dc) qf[dc] = *(const bf16x8*)(qp + dc * 32 + lk);
  }
  float mrow = -1e30f, lsum = 0.f;
  f32x4 o[8];
#pragma unroll
  for (int n = 0; n < 8; ++n) o[n] = (f32x4){0.f, 0.f, 0.f, 0.f};

  attn_tiles(S, Kg, Vtg, pmask, b, q0, tstart, tend, qf, mrow, lsum, o);

  if (nch == 1) {
    const int qrow = q0 + w * 16 + lr;
    const bool alive = pmask[(size_t)b * 4096 + qrow] > 0.f;
    const float inv = (alive && lsum > 0.f) ? 1.f / lsum : 0.f;
    float* op = out + ((size_t)b * 4096 + qrow) * 128 + 4 * lg;
#pragma unroll
    for (int n = 0; n < 8; ++n) {
      f32x4 v = o[n] * inv;
      *(f32x4*)(op + n * 16) = v;
    }
  } else {
    const int slot = (b * 64 + qb) * 4 + c;
    float* op = o_part + ((size_t)slot * 64 + w * 16 + lr) * 128 + 4 * lg;
#pragma unroll
    for (int n = 0; n < 8; ++n) *(f32x4*)(op + n * 16) = o[n];
    if (lane < 16) {
      float* mp = ml_part + ((size_t)slot * 64 + w * 16 + lane) * 2;
      mp[0] = mrow;
      mp[1] = lsum;
    }
  }
}

// ---------- kernel 3c: combine partials (qb >= 16), one wave per output row ----------
__global__ __launch_bounds__(256) void attn_combine(
    const float* __restrict__ o_part, const float* __restrict__ ml_part,
    const float* __restrict__ pmask, float* __restrict__ out) {
  const int tid = threadIdx.x;
  const int lane = tid & 63;
  const int w = tid >> 6;
  const int g = blockIdx.x * 4 + w;      // 0 .. 12287
  const int b = g / 3072;
  const int rem = g % 3072;
  const int qb = 16 + (rem >> 6);
  const int row = rem & 63;
  const int qrow = qb * 64 + row;
  const int nch = (qb >> 4) + 1;         // 2..4
  const int pbase = (b * 64 + qb) * 4;

  float m[4], l[4];
  float M = -1e30f;
  for (int c = 0; c < nch; ++c) {
    const float* mp = ml_part + ((size_t)(pbase + c) * 64 + row) * 2;
    m[c] = mp[0];
    l[c] = mp[1];
    M = fmaxf(M, m[c]);
  }
  float L = 0.f, wgt[4];
  for (int c = 0; c < nch; ++c) {
    wgt[c] = __expf(m[c] - M);
    L += wgt[c] * l[c];
  }
  float2 acc = {0.f, 0.f};
  for (int c = 0; c < nch; ++c) {
    const float2 v = *(const float2*)(o_part + ((size_t)(pbase + c) * 64 + row) * 128 + lane * 2);
    acc.x += wgt[c] * v.x;
    acc.y += wgt[c] * v.y;
  }
  const bool alive = pmask[(size_t)b * 4096 + qrow] > 0.f;
  const float inv = (alive && L > 0.f) ? 1.f / L : 0.f;
  float2* op = (float2*)(out + ((size_t)b * 4096 + qrow) * 128);
  op[lane] = make_float2(acc.x * inv, acc.y * inv);
}

extern "C" void kernel_launch(void* const* d_in, const int* in_sizes, int n_in,
                              void* d_out, int out_size, void* d_ws, size_t ws_size,
                              hipStream_t stream) {
  (void)in_sizes; (void)n_in; (void)out_size;
  const float* x  = (const float*)d_in[0];
  const float* pm = (const float*)d_in[1];
  const float* Wq = (const float*)d_in[2];
  const float* bq = (const float*)d_in[3];
  const float* Wk = (const float*)d_in[4];
  const float* bk = (const float*)d_in[5];
  const float* Wv = (const float*)d_in[6];
  const float* bv = (const float*)d_in[7];
  float* out = (float*)d_out;

  unsigned short* ws  = (unsigned short*)d_ws;
  unsigned short* wt  = ws;                    // 3*128*1024   = 393216 shorts
  unsigned short* Qg  = ws + 393216;           // 16384*128    = 2097152
  unsigned short* Kg  = Qg + 2097152;
  unsigned short* Vtg = Kg + 2097152;          // QKV+wt = 13.37 MB
  float* o_part  = (float*)(ws + 6684672);     // 1024 slots * 64 * 128 f32 = 33.55 MB
  float* ml_part = o_part + 8388608;           // 1024*64*2 f32 = 0.52 MB
  const size_t WS_NEED = 13369344u + (8388608u + 131072u) * 4u;  // 47.45 MB

  convert_w<<<1536, 256, 0, stream>>>(Wq, Wk, Wv, wt);
  qkv_gemm<<<dim3(128, 3), 256, 0, stream>>>(x, wt, bq, bk, bv, Qg, Kg, Vtg);
  if (ws_size >= WS_NEED) {
    attn_split<<<640, 256, 0, stream>>>(Qg, Kg, Vtg, pm, out, o_part, ml_part);
    attn_combine<<<3072, 256, 0, stream>>>(o_part, ml_part, pm, out);
  } else {
    attn_fwd<<<dim3(64, 4), 256, 0, stream>>>(Qg, Kg, Vtg, pm, out);
  }
}

// Round 9
// 115.618 us; speedup vs baseline: 1.1459x; 1.1459x over previous
//
#include <hip/hip_runtime.h>
#include <hip/hip_bf16.h>
#include <cstdint>

typedef __bf16 bf16x8 __attribute__((ext_vector_type(8)));
typedef float f32x4 __attribute__((ext_vector_type(4)));

#define MFMA16(a, b, c) __builtin_amdgcn_mfma_f32_16x16x32_bf16((a), (b), (c), 0, 0, 0)

// ---------- helpers ----------
__device__ __forceinline__ unsigned short f2bf(float f) {
  union { float f; unsigned u; } v; v.f = f;
  unsigned u = v.u;
  u += 0x7fffu + ((u >> 16) & 1u);   // RNE (finite data only)
  return (unsigned short)(u >> 16);
}
__device__ __forceinline__ unsigned pk2(float a, float b) {
  __hip_bfloat162 h = __float22bfloat162_rn(make_float2(a, b));  // v_cvt_pk_bf16_f32
  union { __hip_bfloat162 h; unsigned u; } v; v.h = h; return v.u;
}

// ---------- kernel 1: W [1024][128] f32 -> Wt bf16 [3][128][1024] (n-major) ----------
__global__ __launch_bounds__(256) void convert_w(
    const float* __restrict__ Wq, const float* __restrict__ Wk,
    const float* __restrict__ Wv, unsigned short* __restrict__ wt) {
  int idx = blockIdx.x * 256 + threadIdx.x;     // 0 .. 393215
  int m = idx >> 17;
  int rem = idx & 131071;
  int k = rem >> 7;
  int n = rem & 127;
  const float* W = (m == 0) ? Wq : (m == 1) ? Wk : Wv;
  wt[(size_t)m * 131072 + (size_t)n * 1024 + k] = f2bf(W[(size_t)k * 128 + n]);
}

// ---------- kernel 2: QKV projection GEMM ----------
__global__ __launch_bounds__(256) void qkv_gemm(
    const float* __restrict__ x, const unsigned short* __restrict__ wt_all,
    const float* __restrict__ bq, const float* __restrict__ bk,
    const float* __restrict__ bv,
    unsigned short* __restrict__ Qg, unsigned short* __restrict__ Kg,
    unsigned short* __restrict__ Vtg) {
  __shared__ unsigned short x_lds[128][40];   // +8 pad
  __shared__ unsigned short w_lds[128][40];
  const int tid = threadIdx.x;
  const int lane = tid & 63;
  const int w = tid >> 6;
  const int mode = blockIdx.y;
  const int m0 = blockIdx.x * 128;
  const unsigned short* wt = wt_all + (size_t)mode * 131072;
  const float* bias = (mode == 0) ? bq : (mode == 1) ? bk : bv;

  const int wr = (w >> 1) * 64;
  const int wc = (w & 1) * 64;
  const int lr = lane & 15;
  const int lk = (lane >> 4) * 8;

  f32x4 acc[4][4];
#pragma unroll
  for (int m = 0; m < 4; ++m)
#pragma unroll
    for (int n = 0; n < 4; ++n) acc[m][n] = (f32x4){0.f, 0.f, 0.f, 0.f};

  const int srow = tid >> 1;
  const int shalf = (tid & 1) * 16;
  const float* xrow = x + (size_t)(m0 + srow) * 1024 + shalf;
  const unsigned short* wrow = wt + (size_t)srow * 1024 + shalf;

  float4 xa, xb, xc, xd; uint4 wv0, wv1;
  {
    const float4* s4 = (const float4*)xrow;
    xa = s4[0]; xb = s4[1]; xc = s4[2]; xd = s4[3];
    const uint4* ws4 = (const uint4*)wrow;
    wv0 = ws4[0]; wv1 = ws4[1];
  }

  for (int k0 = 0; k0 < 1024; k0 += 32) {
    __syncthreads();
    {
      uint4 w0, w1;
      w0.x = pk2(xa.x, xa.y);  w0.y = pk2(xa.z, xa.w);
      w0.z = pk2(xb.x, xb.y);  w0.w = pk2(xb.z, xb.w);
      w1.x = pk2(xc.x, xc.y);  w1.y = pk2(xc.z, xc.w);
      w1.z = pk2(xd.x, xd.y);  w1.w = pk2(xd.z, xd.w);
      *(uint4*)&x_lds[srow][shalf] = w0;
      *(uint4*)&x_lds[srow][shalf + 8] = w1;
      *(uint4*)&w_lds[srow][shalf] = wv0;
      *(uint4*)&w_lds[srow][shalf + 8] = wv1;
    }
    __syncthreads();
    if (k0 + 32 < 1024) {
      const float4* s4 = (const float4*)(xrow + k0 + 32);
      xa = s4[0]; xb = s4[1]; xc = s4[2]; xd = s4[3];
      const uint4* ws4 = (const uint4*)(wrow + k0 + 32);
      wv0 = ws4[0]; wv1 = ws4[1];
    }
    bf16x8 af[4], bfr[4];
#pragma unroll
    for (int m = 0; m < 4; ++m) af[m] = *(const bf16x8*)&x_lds[wr + m * 16 + lr][lk];
#pragma unroll
    for (int n = 0; n < 4; ++n) bfr[n] = *(const bf16x8*)&w_lds[wc + n * 16 + lr][lk];
#pragma unroll
    for (int m = 0; m < 4; ++m)
#pragma unroll
      for (int n = 0; n < 4; ++n) acc[m][n] = MFMA16(af[m], bfr[n], acc[m][n]);
  }

  float bcol[4];
#pragma unroll
  for (int n = 0; n < 4; ++n) bcol[n] = bias[wc + n * 16 + lr];
#pragma unroll
  for (int m = 0; m < 4; ++m)
#pragma unroll
    for (int n = 0; n < 4; ++n)
#pragma unroll
      for (int r = 0; r < 4; ++r) {
        int grow = m0 + wr + m * 16 + (lane >> 4) * 4 + r;
        int col = wc + n * 16 + lr;
        float val = acc[m][n][r] + bcol[n];
        if (mode == 0) {
          val *= 0.08838834764831845f;  // 1/sqrt(128)
          Qg[(size_t)grow * 128 + col] = f2bf(val);
        } else if (mode == 1) {
          Kg[(size_t)grow * 128 + col] = f2bf(val);
        } else {
          int bb = grow >> 12, s = grow & 4095;
          Vtg[((size_t)bb * 128 + col) * 4096 + s] = f2bf(val);
        }
      }
}

// ---------- shared attention tile body: swapped QK^T, in-register softmax ----------
// Each lane owns q-row q0+w*16+(lane&15); st[f][r] = S[k=k0+16f+4*lg+r][q_own].
struct AttnLds {
  unsigned short K_lds[64][136];
  unsigned short V_lds[128][72];
  unsigned short P_lds[4][16][68];
};

__device__ __forceinline__ void attn_tiles(
    AttnLds& S, const unsigned short* __restrict__ Kg,
    const unsigned short* __restrict__ Vtg, const float* __restrict__ pmask,
    int b, int q0, int tstart, int tend,
    const bf16x8 (&qf)[4], float& mrow, float& lsum, f32x4 (&o)[8]) {
  const int tid = threadIdx.x;
  const int lane = tid & 63;
  const int w = tid >> 6;
  const int lr = lane & 15;
  const int lg = lane >> 4;
  const int lk = lg * 8;
  const int q_own = q0 + w * 16 + lr;

  for (int t = tstart; t < tend; ++t) {
    const int k0 = t * 64;
    __syncthreads();
    {
      int kr = tid >> 2, seg = (tid & 3) * 32;
      const uint4* src = (const uint4*)(Kg + ((size_t)b * 4096 + k0 + kr) * 128 + seg);
      uint4 v0 = src[0], v1 = src[1], v2 = src[2], v3 = src[3];
      uint4* dst = (uint4*)&S.K_lds[kr][seg];
      dst[0] = v0; dst[1] = v1; dst[2] = v2; dst[3] = v3;
      int d = tid >> 1, half = (tid & 1) * 32;
      const uint4* vs = (const uint4*)(Vtg + ((size_t)b * 128 + d) * 4096 + k0 + half);
      uint4 u0 = vs[0], u1 = vs[1], u2 = vs[2], u3 = vs[3];
      uint4* vdst = (uint4*)&S.V_lds[d][half];
      vdst[0] = u0; vdst[1] = u1; vdst[2] = u2; vdst[3] = u3;
    }
    __syncthreads();

    // S^T: st[f][r] = S[k = k0+16f+4lg+r][q_own]
    f32x4 st[4];
#pragma unroll
    for (int f = 0; f < 4; ++f) {
      st[f] = (f32x4){0.f, 0.f, 0.f, 0.f};
#pragma unroll
      for (int dc = 0; dc < 4; ++dc) {
        bf16x8 kf = *(const bf16x8*)&S.K_lds[f * 16 + lr][dc * 32 + lk];
        st[f] = MFMA16(kf, qf[dc], st[f]);   // swapped: K as A, Q as B
      }
    }

    // padding mask via ballot (one coalesced load per wave)
    const unsigned long long mb = __ballot(pmask[(size_t)b * 4096 + k0 + lane] > 0.f);
    unsigned nib[4];
#pragma unroll
    for (int f = 0; f < 4; ++f) nib[f] = (unsigned)(mb >> (16 * f + 4 * lg)) & 0xFu;

    float mx = -1e30f;
    if (k0 + 63 > q0 + (w << 4)) {           // diagonal tile: causal + pad
#pragma unroll
      for (int f = 0; f < 4; ++f)
#pragma unroll
        for (int r = 0; r < 4; ++r) {
          const bool ok = (((nib[f] >> r) & 1u) != 0u) &&
                          (k0 + 16 * f + 4 * lg + r <= q_own);
          const float s = ok ? st[f][r] : -1e30f;
          st[f][r] = s;
          mx = fmaxf(mx, s);
        }
    } else {                                  // interior tile: pad mask only
#pragma unroll
      for (int f = 0; f < 4; ++f)
#pragma unroll
        for (int r = 0; r < 4; ++r) {
          const bool ok = ((nib[f] >> r) & 1u) != 0u;
          const float s = ok ? st[f][r] : -1e30f;
          st[f][r] = s;
          mx = fmaxf(mx, s);
        }
    }
    mx = fmaxf(mx, __shfl_xor(mx, 16));
    mx = fmaxf(mx, __shfl_xor(mx, 32));
    const float mnew = fmaxf(mrow, mx);
    const float alpha = __expf(mrow - mnew);
    mrow = mnew;

    float sum = 0.f;
#pragma unroll
    for (int f = 0; f < 4; ++f) {
      const float p0 = (st[f][0] < -1e29f) ? 0.f : __expf(st[f][0] - mnew);
      const float p1 = (st[f][1] < -1e29f) ? 0.f : __expf(st[f][1] - mnew);
      const float p2 = (st[f][2] < -1e29f) ? 0.f : __expf(st[f][2] - mnew);
      const float p3 = (st[f][3] < -1e29f) ? 0.f : __expf(st[f][3] - mnew);
      sum += (p0 + p1) + (p2 + p3);
      uint2 u; u.x = pk2(p0, p1); u.y = pk2(p2, p3);
      *(uint2*)&S.P_lds[w][lr][16 * f + 4 * lg] = u;   // P[q_own][k-chunk]
    }
    sum += __shfl_xor(sum, 16);
    sum += __shfl_xor(sum, 32);
    lsum = lsum * alpha + sum;
#pragma unroll
    for (int n = 0; n < 8; ++n) o[n] *= alpha;

    __asm__ volatile("s_waitcnt lgkmcnt(0)" ::: "memory");
    // O^T: o[n][r] = O[q_own][d = n*16+4lg+r]
#pragma unroll
    for (int kc = 0; kc < 2; ++kc) {
      bf16x8 pa = *(const bf16x8*)&S.P_lds[w][lr][kc * 32 + lk];
#pragma unroll
      for (int n = 0; n < 8; ++n) {
        bf16x8 vf = *(const bf16x8*)&S.V_lds[n * 16 + lr][kc * 32 + lk];
        o[n] = MFMA16(vf, pa, o[n]);         // swapped: V as A, P as B
      }
    }
  }
}

// ---------- kernel 3a: fallback monolithic flash attention ----------
__global__ __launch_bounds__(256) void attn_fwd(
    const unsigned short* __restrict__ Qg, const unsigned short* __restrict__ Kg,
    const unsigned short* __restrict__ Vtg, const float* __restrict__ pmask,
    float* __restrict__ out) {
  __shared__ AttnLds S;
  const int tid = threadIdx.x;
  const int lane = tid & 63;
  const int w = tid >> 6;
  const int b = blockIdx.y;
  const int q0 = blockIdx.x * 64;
  const int lr = lane & 15;
  const int lg = lane >> 4;
  const int lk = lg * 8;

  bf16x8 qf[4];
  {
    const unsigned short* qp = Qg + ((size_t)b * 4096 + q0 + w * 16 + lr) * 128;
#pragma unroll
    for (int dc = 0; dc < 4; ++dc) qf[dc] = *(const bf16x8*)(qp + dc * 32 + lk);
  }
  float mrow = -1e30f, lsum = 0.f;
  f32x4 o[8];
#pragma unroll
  for (int n = 0; n < 8; ++n) o[n] = (f32x4){0.f, 0.f, 0.f, 0.f};

  attn_tiles(S, Kg, Vtg, pmask, b, q0, 0, (q0 >> 6) + 1, qf, mrow, lsum, o);

  const int qrow = q0 + w * 16 + lr;
  const bool alive = pmask[(size_t)b * 4096 + qrow] > 0.f;
  const float inv = (alive && lsum > 0.f) ? 1.f / lsum : 0.f;
  float* op = out + ((size_t)b * 4096 + qrow) * 128 + 4 * lg;
#pragma unroll
  for (int n = 0; n < 8; ++n) {
    f32x4 v = o[n] * inv;
    *(f32x4*)(op + n * 16) = v;
  }
}

// ---------- kernel 3b: split-KV flash attention, XCD-pinned, chunk=13, bf16 partials ----------
// 760 blocks (<= 768 co-resident at 3 blocks/CU). xcd = L&7; batch = xcd>>1;
// s = 0..189 within batch. nch(qb) = ceil((qb+1)/13) in 1..5.
__global__ __launch_bounds__(256) void attn_split(
    const unsigned short* __restrict__ Qg, const unsigned short* __restrict__ Kg,
    const unsigned short* __restrict__ Vtg, const float* __restrict__ pmask,
    float* __restrict__ out, unsigned short* __restrict__ o_part,
    float* __restrict__ ml_part) {
  __shared__ AttnLds S;
  const int tid = threadIdx.x;
  const int lane = tid & 63;
  const int w = tid >> 6;
  const int L = blockIdx.x;
  const int xcd = L & 7;
  const int b = xcd >> 1;
  const int s = ((L >> 3) << 1) | (xcd & 1);   // 0..189 within batch
  int qb, c, nch;
  if (s < 13)       { qb = s;                 c = 0;       nch = 1; }
  else if (s < 39)  { int t = s - 13;  qb = 13 + (t >> 1); c = t & 1;  nch = 2; }
  else if (s < 78)  { int t = s - 39;  qb = 26 + t / 3;    c = t % 3;  nch = 3; }
  else if (s < 130) { int t = s - 78;  qb = 39 + (t >> 2); c = t & 3;  nch = 4; }
  else              { int t = s - 130; qb = 52 + t / 5;    c = t % 5;  nch = 5; }
  const int q0 = qb * 64;
  const int tstart = c * 13;
  const int tend = min(c * 13 + 13, qb + 1);
  const int lr = lane & 15;
  const int lg = lane >> 4;
  const int lk = lg * 8;

  bf16x8 qf[4];
  {
    const unsigned short* qp = Qg + ((size_t)b * 4096 + q0 + w * 16 + lr) * 128;
#pragma unroll
    for (int dc = 0; dc < 4; ++dc) qf[dc] = *(const bf16x8*)(qp + dc * 32 + lk);
  }
  float mrow = -1e30f, lsum = 0.f;
  f32x4 o[8];
#pragma unroll
  for (int n = 0; n < 8; ++n) o[n] = (f32x4){0.f, 0.f, 0.f, 0.f};

  attn_tiles(S, Kg, Vtg, pmask, b, q0, tstart, tend, qf, mrow, lsum, o);

  if (nch == 1) {
    const int qrow = q0 + w * 16 + lr;
    const bool alive = pmask[(size_t)b * 4096 + qrow] > 0.f;
    const float inv = (alive && lsum > 0.f) ? 1.f / lsum : 0.f;
    float* op = out + ((size_t)b * 4096 + qrow) * 128 + 4 * lg;
#pragma unroll
    for (int n = 0; n < 8; ++n) {
      f32x4 v = o[n] * inv;
      *(f32x4*)(op + n * 16) = v;
    }
  } else {
    const int slot = (b * 64 + qb) * 5 + c;
    unsigned short* op = o_part + ((size_t)slot * 64 + w * 16 + lr) * 128 + 4 * lg;
#pragma unroll
    for (int n = 0; n < 8; ++n) {
      uint2 u; u.x = pk2(o[n][0], o[n][1]); u.y = pk2(o[n][2], o[n][3]);
      *(uint2*)(op + n * 16) = u;
    }
    if (lane < 16) {
      float* mp = ml_part + ((size_t)slot * 64 + w * 16 + lane) * 2;
      mp[0] = mrow;
      mp[1] = lsum;
    }
  }
}

// ---------- kernel 3c: combine partials (qb >= 13), one wave per output row ----------
__global__ __launch_bounds__(256) void attn_combine(
    const unsigned short* __restrict__ o_part, const float* __restrict__ ml_part,
    const float* __restrict__ pmask, float* __restrict__ out) {
  const int tid = threadIdx.x;
  const int lane = tid & 63;
  const int w = tid >> 6;
  const int g = blockIdx.x * 4 + w;      // 0 .. 13055
  const int b = g / 3264;
  const int rem = g % 3264;
  const int qb = 13 + (rem >> 6);
  const int row = rem & 63;
  const int qrow = qb * 64 + row;
  const int nch = (qb + 13) / 13;        // 2..5
  const int pbase = (b * 64 + qb) * 5;

  float m[5], l[5];
  float M = -1e30f;
  for (int c = 0; c < nch; ++c) {
    const float* mp = ml_part + ((size_t)(pbase + c) * 64 + row) * 2;
    m[c] = mp[0];
    l[c] = mp[1];
    M = fmaxf(M, m[c]);
  }
  float L = 0.f, wgt[5];
  for (int c = 0; c < nch; ++c) {
    wgt[c] = __expf(m[c] - M);
    L += wgt[c] * l[c];
  }
  float2 acc = {0.f, 0.f};
  for (int c = 0; c < nch; ++c) {
    const unsigned u = *(const unsigned*)(o_part + ((size_t)(pbase + c) * 64 + row) * 128 + lane * 2);
    acc.x += wgt[c] * __uint_as_float(u << 16);
    acc.y += wgt[c] * __uint_as_float(u & 0xffff0000u);
  }
  const bool alive = pmask[(size_t)b * 4096 + qrow] > 0.f;
  const float inv = (alive && L > 0.f) ? 1.f / L : 0.f;
  float2* op = (float2*)(out + ((size_t)b * 4096 + qrow) * 128);
  op[lane] = make_float2(acc.x * inv, acc.y * inv);
}

extern "C" void kernel_launch(void* const* d_in, const int* in_sizes, int n_in,
                              void* d_out, int out_size, void* d_ws, size_t ws_size,
                              hipStream_t stream) {
  (void)in_sizes; (void)n_in; (void)out_size;
  const float* x  = (const float*)d_in[0];
  const float* pm = (const float*)d_in[1];
  const float* Wq = (const float*)d_in[2];
  const float* bq = (const float*)d_in[3];
  const float* Wk = (const float*)d_in[4];
  const float* bk = (const float*)d_in[5];
  const float* Wv = (const float*)d_in[6];
  const float* bv = (const float*)d_in[7];
  float* out = (float*)d_out;

  unsigned short* ws  = (unsigned short*)d_ws;
  unsigned short* wt  = ws;                    // 3*128*1024   = 393216 shorts
  unsigned short* Qg  = ws + 393216;           // 16384*128    = 2097152
  unsigned short* Kg  = Qg + 2097152;
  unsigned short* Vtg = Kg + 2097152;          // QKV+wt = 13.37 MB
  unsigned short* o_part = ws + 6684672;       // 1280 slots * 64 * 128 bf16 = 21.0 MB
  float* ml_part = (float*)(ws + 17170432);    // 1280*64*2 f32 = 0.66 MB
  const size_t WS_NEED = 34996224u;            // 35.0 MB

  convert_w<<<1536, 256, 0, stream>>>(Wq, Wk, Wv, wt);
  qkv_gemm<<<dim3(128, 3), 256, 0, stream>>>(x, wt, bq, bk, bv, Qg, Kg, Vtg);
  if (ws_size >= WS_NEED) {
    attn_split<<<760, 256, 0, stream>>>(Qg, Kg, Vtg, pm, out, o_part, ml_part);
    attn_combine<<<3264, 256, 0, stream>>>(o_part, ml_part, pm, out);
  } else {
    attn_fwd<<<dim3(64, 4), 256, 0, stream>>>(Qg, Kg, Vtg, pm, out);
  }
}